// Round 10
// baseline (70.268 us; speedup 1.0000x reference)
//
#include <hip/hip_runtime.h>

#define Nn 4096
#define NTRI 528              // 32*33/2 upper-tri 128x128 tiles
#define NBLK 2080             // 2*528 + 1024
#define REP 3                 // DIAGNOSTIC: repeat tile body to surface in rocprof top-5

typedef __attribute__((ext_vector_type(4))) float f32x4;

#define C_K   0.7213475204444817f   // log2(e)/mu, mu=2
#define C_2K  1.4426950408889634f   // 2*log2(e)/mu
#define SKIP_BOUND -40.0f           // exp2(-40)*16.7M*beta ~ 1e-19 << 1e-5 threshold

// manual f32 -> fp8 e4m3fn (RNE, FTZ below 2^-6, saturate to 448)
__device__ __forceinline__ unsigned f2e4m3(float f) {
  unsigned u = __float_as_uint(f);
  unsigned s = (u >> 24) & 0x80u;
  int e = (int)((u >> 23) & 0xff);
  unsigned m = u & 0x7fffffu;
  if (e < 121) return s;                         // FTZ (|x| < 2^-6), incl. zero
  unsigned mr = m + 0x7ffffu + ((m >> 20) & 1u); // RNE to 3 mantissa bits
  if (mr & 0x800000u) { mr = 0; e += 1; }
  int code = ((e - 120) << 3) | (int)(mr >> 20);
  if (code > 0x7e) code = 0x7e;                  // clamp to 448 (no inf/nan)
  return s | (unsigned)code;
}

__device__ __forceinline__ void gload_lds16(const void* g, void* l) {
  __builtin_amdgcn_global_load_lds(
      (const __attribute__((address_space(1))) unsigned int*)g,
      (__attribute__((address_space(3))) unsigned int*)l, 16, 0, 0);
}

// ---- prep: fp8 cast + prescaled norms kn[row] = -K * ||row||^2 --------------
__global__ __launch_bounds__(256) void prep_kernel(const float* __restrict__ X,
                                                   const float* __restrict__ Y,
                                                   float* __restrict__ kn,
                                                   unsigned char* __restrict__ Xq,
                                                   unsigned char* __restrict__ Yq) {
  int wave = threadIdx.x >> 6;
  int lane = threadIdx.x & 63;
  int row = blockIdx.x * 4 + wave;            // 0..8191
  const float* src;
  unsigned char* dst;
  if (row < Nn) { src = X + (size_t)row * 128;        dst = Xq + (size_t)row * 128; }
  else          { src = Y + (size_t)(row - Nn) * 128; dst = Yq + (size_t)(row - Nn) * 128; }
  float2 v = reinterpret_cast<const float2*>(src)[lane];
  float s = v.x * v.x + v.y * v.y;
#pragma unroll
  for (int off = 32; off > 0; off >>= 1) s += __shfl_xor(s, off);
  unsigned short h = (unsigned short)(f2e4m3(v.x) | (f2e4m3(v.y) << 8));
  reinterpret_cast<unsigned short*>(dst)[lane] = h;
  if (lane == 0) kn[row] = -C_K * s;
}

// ---- fused pairwise-exp-sum (r6 structure), tile body repeated REP times -----
// t < 528:        q=0 (XX), upper-tri tile (by<=bx), off-diag weight 2
// 528 <= t <1056: q=1 (YY), same
// t >= 1056:      q=2 (XY), full 32x32
__global__ __launch_bounds__(256, 4) void mmd_main(const unsigned char* __restrict__ Xq,
                                                   const unsigned char* __restrict__ Yq,
                                                   const float* __restrict__ kn,
                                                   float* __restrict__ partials) {
  __shared__ __align__(16) char As[128 * 128];
  __shared__ __align__(16) char Bs[128 * 128];
  __shared__ float red[4];

  const int t = blockIdx.x;
  int q, bx, by;
  if (t < 2 * NTRI) {
    q = (t >= NTRI) ? 1 : 0;
    const int u = t - q * NTRI;
    int r = (int)((sqrtf(8.f * (float)u + 1.f) - 1.f) * 0.5f);
    while ((r + 1) * (r + 2) / 2 <= u) ++r;
    while (r * (r + 1) / 2 > u) --r;
    bx = r; by = u - r * (r + 1) / 2;          // by <= bx
  } else {
    q = 2;
    const int u = t - 2 * NTRI;
    by = u >> 5; bx = u & 31;
  }

  const unsigned char* Asrc = (q == 1) ? Yq : Xq;
  const unsigned char* Bsrc = (q == 0) ? Xq : Yq;
  const float* knA = (q == 1) ? kn + Nn : kn;
  const float* knB = (q == 0) ? kn : kn + Nn;
  const int R0 = by << 7, C0 = bx << 7;

  const int lane = threadIdx.x & 63;
  const int wv   = threadIdx.x >> 6;
  const int wr = wv >> 1, wc = wv & 1;    // 2x2 wave grid, 64x64 per wave
  const int lr = lane & 15, kq = lane >> 4;
  const bool diagblk = (q < 2) && (bx == by);

#pragma unroll 1
  for (int rep = 0; rep < REP; ++rep) {
    __syncthreads();                       // prior rep's LDS readers done

    // ---- stage: 4+4 gload_lds16 per wave (fp8 swizzle p = u ^ (r&7)) --------
    {
      const int rg = lane >> 3;                      // row within 8-row group
      const int uu = (lane & 7) ^ (rg & 7);          // logical unit for this slot
      const char* Ag = (const char*)Asrc + ((size_t)(R0 + (wv << 5) + rg) << 7) + (uu << 4);
      const char* Bg = (const char*)Bsrc + ((size_t)(C0 + (wv << 5) + rg) << 7) + (uu << 4);
#pragma unroll
      for (int i = 0; i < 4; ++i) {                  // 4 x 8-row groups = 32 rows/wave
        gload_lds16(Ag + (i << 10), As + (wv << 12) + (i << 10));
        gload_lds16(Bg + (i << 10), Bs + (wv << 12) + (i << 10));
      }
    }
    __syncthreads();

    // ---- MFMA: 4 k-steps of 32 (fp8), 16 fragments per wave ------------------
    f32x4 acc[4][4];
#pragma unroll
    for (int m = 0; m < 4; ++m)
#pragma unroll
      for (int n = 0; n < 4; ++n)
        acc[m][n] = (f32x4){0.f, 0.f, 0.f, 0.f};

#pragma unroll
    for (int ks = 0; ks < 4; ++ks) {
      const int uf = (ks << 1) + (kq >> 1);          // logical 16B unit of this frag
      const int hb = (kq & 1) << 3;                  // 8B half within the unit
      long a[4], b[4];
#pragma unroll
      for (int m = 0; m < 4; ++m) {
        const int row = (wr << 6) + (m << 4) + lr;
        a[m] = *reinterpret_cast<const long*>(As + (row << 7) + ((uf ^ (lr & 7)) << 4) + hb);
      }
#pragma unroll
      for (int n = 0; n < 4; ++n) {
        const int row = (wc << 6) + (n << 4) + lr;
        b[n] = *reinterpret_cast<const long*>(Bs + (row << 7) + ((uf ^ (lr & 7)) << 4) + hb);
      }
#pragma unroll
      for (int m = 0; m < 4; ++m)
#pragma unroll
        for (int n = 0; n < 4; ++n)
          acc[m][n] = __builtin_amdgcn_mfma_f32_16x16x32_fp8_fp8(a[m], b[n], acc[m][n], 0, 0, 0);
    }

    // ---- epilogue: wave-level underflow skip, then exp2 ----------------------
    f32x4 ax[4];
    float cy[4];
#pragma unroll
    for (int m = 0; m < 4; ++m)
      ax[m] = *reinterpret_cast<const f32x4*>(knA + R0 + (wr << 6) + (m << 4) + (kq << 2));
#pragma unroll
    for (int n = 0; n < 4; ++n)
      cy[n] = knB[C0 + (wc << 6) + (n << 4) + lr];

    f32x4 vm = acc[0][0];
#pragma unroll
    for (int m = 0; m < 4; ++m)
#pragma unroll
      for (int n = 0; n < 4; ++n) {
        if (m == 0 && n == 0) continue;
        vm[0] = fmaxf(vm[0], acc[m][n][0]);
        vm[1] = fmaxf(vm[1], acc[m][n][1]);
        vm[2] = fmaxf(vm[2], acc[m][n][2]);
        vm[3] = fmaxf(vm[3], acc[m][n][3]);
      }
    float amax = fmaxf(fmaxf(vm[0], vm[1]), fmaxf(vm[2], vm[3]));
    float axm = -1e30f;
#pragma unroll
    for (int m = 0; m < 4; ++m)
      axm = fmaxf(axm, fmaxf(fmaxf(ax[m][0], ax[m][1]), fmaxf(ax[m][2], ax[m][3])));
    float cym = fmaxf(fmaxf(cy[0], cy[1]), fmaxf(cy[2], cy[3]));
    float bound = fmaf(amax, C_2K, axm + cym);

    float local = 0.f;
    if (__any(bound > SKIP_BOUND)) {
      float l0 = 0.f, l1 = 0.f, l2 = 0.f, l3 = 0.f;
#pragma unroll
      for (int m = 0; m < 4; ++m) {
        const int rbase = (wr << 6) + (m << 4) + (kq << 2);
#pragma unroll
        for (int n = 0; n < 4; ++n) {
          const float e0 = __builtin_amdgcn_exp2f(fmaf(acc[m][n][0], C_2K, ax[m][0] + cy[n]));
          const float e1 = __builtin_amdgcn_exp2f(fmaf(acc[m][n][1], C_2K, ax[m][1] + cy[n]));
          const float e2 = __builtin_amdgcn_exp2f(fmaf(acc[m][n][2], C_2K, ax[m][2] + cy[n]));
          const float e3 = __builtin_amdgcn_exp2f(fmaf(acc[m][n][3], C_2K, ax[m][3] + cy[n]));
          if (diagblk) {
            const int cc = (wc << 6) + (n << 4) + lr;
            if (rbase + 0 != cc) l0 += e0;
            if (rbase + 1 != cc) l1 += e1;
            if (rbase + 2 != cc) l2 += e2;
            if (rbase + 3 != cc) l3 += e3;
          } else {
            l0 += e0; l1 += e1; l2 += e2; l3 += e3;
          }
        }
      }
      local = (l0 + l1) + (l2 + l3);
#pragma unroll
      for (int off = 32; off > 0; off >>= 1) local += __shfl_xor(local, off);
    }

    if (lane == 0) red[wv] = local;
    __syncthreads();
    if (threadIdx.x == 0) {
      float s = (red[0] + red[1]) + (red[2] + red[3]);
      float w;
      if (q < 2) w = ((bx == by) ? 1.f : 2.f) * (1.0f / 16773120.0f);  // alpha
      else       w = -2.0f / 16777216.0f;                               // -2*beta
      partials[t] = s * w;     // identical value every rep (keeps body live, rule #17)
    }
  }
}

// ---- deterministic final reduction ------------------------------------------
__global__ __launch_bounds__(256) void mmd_final(const float* __restrict__ partials,
                                                 float* __restrict__ out) {
  float v = 0.f;
  for (int i = threadIdx.x; i < NBLK; i += 256) v += partials[i];
#pragma unroll
  for (int off = 32; off > 0; off >>= 1) v += __shfl_xor(v, off);
  __shared__ float red[4];
  if ((threadIdx.x & 63) == 0) red[threadIdx.x >> 6] = v;
  __syncthreads();
  if (threadIdx.x == 0) {
    // analytic diagonal: n*(alpha1+alpha2) = 2/4095
    out[0] = ((red[0] + red[1]) + (red[2] + red[3])) + (float)(2.0 / 4095.0);
  }
}

extern "C" void kernel_launch(void* const* d_in, const int* in_sizes, int n_in,
                              void* d_out, int out_size, void* d_ws, size_t ws_size,
                              hipStream_t stream) {
  const float* X = (const float*)d_in[0];
  const float* Y = (const float*)d_in[1];
  float* kn       = (float*)d_ws;                       // 8192 floats (-K*norm^2)
  float* partials = kn + 8192;                          // 2080 floats
  unsigned char* Xq = (unsigned char*)(partials + 2080);   // 4096*128 fp8 (16B-aligned)
  unsigned char* Yq = Xq + (size_t)Nn * 128;
  float* out = (float*)d_out;

  hipLaunchKernelGGL(prep_kernel, dim3(2048), dim3(256), 0, stream, X, Y, kn, Xq, Yq);
  hipLaunchKernelGGL(mmd_main, dim3(NBLK), dim3(256), 0, stream, Xq, Yq, kn, partials);
  hipLaunchKernelGGL(mmd_final, dim3(1), dim3(256), 0, stream, partials, out);
}

// Round 11
// 20.917 us; speedup vs baseline: 3.3593x; 3.3593x over previous
//
#include <hip/hip_runtime.h>

#define Nn 4096
#define NTRI 528              // 32*33/2 upper-tri 128x128 tiles
#define NBLK 2080             // 2*528 + 1024

typedef __attribute__((ext_vector_type(4))) float f32x4;
typedef __attribute__((ext_vector_type(2))) long  long2v;

#define C_K   0.7213475204444817f   // log2(e)/mu, mu=2
#define C_2K  1.4426950408889634f   // 2*log2(e)/mu
#define SKIP_BOUND -40.0f           // exp2(-40)*16.7M*beta ~ 1e-19 << 1e-5 threshold

// manual f32 -> fp8 e4m3fn (RNE, FTZ below 2^-6, saturate to 448)
__device__ __forceinline__ unsigned f2e4m3(float f) {
  unsigned u = __float_as_uint(f);
  unsigned s = (u >> 24) & 0x80u;
  int e = (int)((u >> 23) & 0xff);
  unsigned m = u & 0x7fffffu;
  if (e < 121) return s;                         // FTZ (|x| < 2^-6), incl. zero
  unsigned mr = m + 0x7ffffu + ((m >> 20) & 1u); // RNE to 3 mantissa bits
  if (mr & 0x800000u) { mr = 0; e += 1; }
  int code = ((e - 120) << 3) | (int)(mr >> 20);
  if (code > 0x7e) code = 0x7e;                  // clamp to 448 (no inf/nan)
  return s | (unsigned)code;
}

__device__ __forceinline__ void gload_lds16(const void* g, void* l) {
  __builtin_amdgcn_global_load_lds(
      (const __attribute__((address_space(1))) unsigned int*)g,
      (__attribute__((address_space(3))) unsigned int*)l, 16, 0, 0);
}

// ---- prep: fp8 cast into FRAGMENT-NATIVE layout + norms ----------------------
// Layout: 16-row panel p, ks-pair c in {0,1}, MFMA lane L = kq*16 + (row&15):
//   byte offset = p*2048 + c*1024 + L*16 + (ks&1)*8 + (k&7)
// where k = column byte, ks = k>>5, kq = (k>>3)&3.  A wave's fragment read is
// then ds_read_b128 at (base + lane*16): 1024B linear -> zero bank conflicts;
// staging is plain contiguous global_load_lds (no swizzle anywhere).
__global__ __launch_bounds__(256) void prep_kernel(const float* __restrict__ X,
                                                   const float* __restrict__ Y,
                                                   float* __restrict__ kn,
                                                   unsigned char* __restrict__ Xf,
                                                   unsigned char* __restrict__ Yf) {
  int wave = threadIdx.x >> 6;
  int lane = threadIdx.x & 63;
  int row = blockIdx.x * 4 + wave;            // 0..8191
  const float* src;
  unsigned char* dstm;
  int r;
  if (row < Nn) { r = row;      src = X + (size_t)r * 128; dstm = Xf; }
  else          { r = row - Nn; src = Y + (size_t)r * 128; dstm = Yf; }
  float2 v = reinterpret_cast<const float2*>(src)[lane];
  float s = v.x * v.x + v.y * v.y;
#pragma unroll
  for (int off = 32; off > 0; off >>= 1) s += __shfl_xor(s, off);
  unsigned short h = (unsigned short)(f2e4m3(v.x) | (f2e4m3(v.y) << 8));
  // this lane covers bytes k = 2*lane, 2*lane+1 of row r
  const int c    = lane >> 5;                 // (k>>5)>>1
  const int half = (lane >> 4) & 1;           // ks & 1
  const int kq   = (lane >> 2) & 3;
  const int L    = (kq << 4) + (r & 15);
  const size_t off8 = ((size_t)(r >> 4) << 11) + (c << 10) + (L << 4)
                    + (half << 3) + ((lane & 3) << 1);
  *reinterpret_cast<unsigned short*>(dstm + off8) = h;
  if (lane == 0) kn[row] = -C_K * s;
}

// ---- fused pairwise-exp-sum: fragment-native LDS, conflict-free, no spill ----
// t < 528:        q=0 (XX), upper-tri tile (by<=bx), off-diag weight 2
// 528 <= t <1056: q=1 (YY), same
// t >= 1056:      q=2 (XY), full 32x32
// __launch_bounds__(256,2): unified VGPR+AGPR cap 256 (kernel needs ~170) -> NO
// scratch spill (r10 PMC: (256,4)'s 128-reg cap caused 145MB/dispatch spill).
__global__ __launch_bounds__(256, 2) void mmd_main(const unsigned char* __restrict__ Xf,
                                                   const unsigned char* __restrict__ Yf,
                                                   const float* __restrict__ kn,
                                                   float* __restrict__ partials) {
  __shared__ __align__(16) char As[16384];
  __shared__ __align__(16) char Bs[16384];
  __shared__ float red[4];

  const int t = blockIdx.x;
  int q, bx, by;
  if (t < 2 * NTRI) {
    q = (t >= NTRI) ? 1 : 0;
    const int u = t - q * NTRI;
    int r = (int)((sqrtf(8.f * (float)u + 1.f) - 1.f) * 0.5f);
    while ((r + 1) * (r + 2) / 2 <= u) ++r;
    while (r * (r + 1) / 2 > u) --r;
    bx = r; by = u - r * (r + 1) / 2;          // by <= bx
  } else {
    q = 2;
    const int u = t - 2 * NTRI;
    by = u >> 5; bx = u & 31;
  }

  const unsigned char* Asrc = (q == 1) ? Yf : Xf;
  const unsigned char* Bsrc = (q == 0) ? Xf : Yf;
  const float* knA = (q == 1) ? kn + Nn : kn;
  const float* knB = (q == 0) ? kn : kn + Nn;
  const int R0 = by << 7, C0 = bx << 7;

  const int lane = threadIdx.x & 63;
  const int wv   = threadIdx.x >> 6;
  const int wr = wv >> 1, wc = wv & 1;    // 2x2 wave grid, 64x64 per wave
  const int lr = lane & 15, kq = lane >> 4;

  // ---- stage: contiguous global_load_lds, 4+4 per wave (2 panels/operand) ----
  {
    const char* Ag = (const char*)Asrc + ((size_t)((by << 3) + (wv << 1)) << 11) + (lane << 4);
    const char* Bg = (const char*)Bsrc + ((size_t)((bx << 3) + (wv << 1)) << 11) + (lane << 4);
    char* dA = As + (wv << 12);
    char* dB = Bs + (wv << 12);
#pragma unroll
    for (int j = 0; j < 4; ++j) {          // 2 panels x 2 chunks = 4 KB per operand
      gload_lds16(Ag + (j << 10), dA + (j << 10));
      gload_lds16(Bg + (j << 10), dB + (j << 10));
    }
  }
  __syncthreads();

  // ---- fragment loads: 16x ds_read_b128, linear (base + lane*16) -------------
  long af[4][4], bf[4][4];                 // [ks][m]
#pragma unroll
  for (int i = 0; i < 4; ++i)
#pragma unroll
    for (int c = 0; c < 2; ++c) {
      long2v ta = *reinterpret_cast<const long2v*>(
          As + ((((wr << 2) + i) << 11) + (c << 10) + (lane << 4)));
      af[(c << 1)][i]     = ta[0];
      af[(c << 1) + 1][i] = ta[1];
      long2v tb = *reinterpret_cast<const long2v*>(
          Bs + ((((wc << 2) + i) << 11) + (c << 10) + (lane << 4)));
      bf[(c << 1)][i]     = tb[0];
      bf[(c << 1) + 1][i] = tb[1];
    }

  f32x4 acc[4][4];
#pragma unroll
  for (int m = 0; m < 4; ++m)
#pragma unroll
    for (int n = 0; n < 4; ++n)
      acc[m][n] = (f32x4){0.f, 0.f, 0.f, 0.f};

#pragma unroll
  for (int ks = 0; ks < 4; ++ks)
#pragma unroll
    for (int m = 0; m < 4; ++m)
#pragma unroll
      for (int n = 0; n < 4; ++n)
        acc[m][n] = __builtin_amdgcn_mfma_f32_16x16x32_fp8_fp8(af[ks][m], bf[ks][n],
                                                               acc[m][n], 0, 0, 0);

  // ---- epilogue: wave-level underflow skip, then exp2 -------------------------
  const bool diagblk = (q < 2) && (bx == by);
  f32x4 ax[4];
  float cy[4];
#pragma unroll
  for (int m = 0; m < 4; ++m)
    ax[m] = *reinterpret_cast<const f32x4*>(knA + R0 + (wr << 6) + (m << 4) + (kq << 2));
#pragma unroll
  for (int n = 0; n < 4; ++n)
    cy[n] = knB[C0 + (wc << 6) + (n << 4) + lr];

  f32x4 vm = acc[0][0];
#pragma unroll
  for (int m = 0; m < 4; ++m)
#pragma unroll
    for (int n = 0; n < 4; ++n) {
      if (m == 0 && n == 0) continue;
      vm[0] = fmaxf(vm[0], acc[m][n][0]);
      vm[1] = fmaxf(vm[1], acc[m][n][1]);
      vm[2] = fmaxf(vm[2], acc[m][n][2]);
      vm[3] = fmaxf(vm[3], acc[m][n][3]);
    }
  float amax = fmaxf(fmaxf(vm[0], vm[1]), fmaxf(vm[2], vm[3]));
  float axm = -1e30f;
#pragma unroll
  for (int m = 0; m < 4; ++m)
    axm = fmaxf(axm, fmaxf(fmaxf(ax[m][0], ax[m][1]), fmaxf(ax[m][2], ax[m][3])));
  float cym = fmaxf(fmaxf(cy[0], cy[1]), fmaxf(cy[2], cy[3]));
  float bound = fmaf(amax, C_2K, axm + cym);

  float local = 0.f;
  if (__any(bound > SKIP_BOUND)) {
    float l0 = 0.f, l1 = 0.f, l2 = 0.f, l3 = 0.f;
#pragma unroll
    for (int m = 0; m < 4; ++m) {
      const int rbase = (wr << 6) + (m << 4) + (kq << 2);
#pragma unroll
      for (int n = 0; n < 4; ++n) {
        const float e0 = __builtin_amdgcn_exp2f(fmaf(acc[m][n][0], C_2K, ax[m][0] + cy[n]));
        const float e1 = __builtin_amdgcn_exp2f(fmaf(acc[m][n][1], C_2K, ax[m][1] + cy[n]));
        const float e2 = __builtin_amdgcn_exp2f(fmaf(acc[m][n][2], C_2K, ax[m][2] + cy[n]));
        const float e3 = __builtin_amdgcn_exp2f(fmaf(acc[m][n][3], C_2K, ax[m][3] + cy[n]));
        if (diagblk) {
          const int cc = (wc << 6) + (n << 4) + lr;
          if (rbase + 0 != cc) l0 += e0;
          if (rbase + 1 != cc) l1 += e1;
          if (rbase + 2 != cc) l2 += e2;
          if (rbase + 3 != cc) l3 += e3;
        } else {
          l0 += e0; l1 += e1; l2 += e2; l3 += e3;
        }
      }
    }
    local = (l0 + l1) + (l2 + l3);
#pragma unroll
    for (int off = 32; off > 0; off >>= 1) local += __shfl_xor(local, off);
  }

  if (lane == 0) red[wv] = local;
  __syncthreads();
  if (threadIdx.x == 0) {
    float s = (red[0] + red[1]) + (red[2] + red[3]);
    float w;
    if (q < 2) w = ((bx == by) ? 1.f : 2.f) * (1.0f / 16773120.0f);  // alpha
    else       w = -2.0f / 16777216.0f;                               // -2*beta
    partials[t] = s * w;
  }
}

// ---- deterministic final reduction ------------------------------------------
__global__ __launch_bounds__(256) void mmd_final(const float* __restrict__ partials,
                                                 float* __restrict__ out) {
  float v = 0.f;
  for (int i = threadIdx.x; i < NBLK; i += 256) v += partials[i];
#pragma unroll
  for (int off = 32; off > 0; off >>= 1) v += __shfl_xor(v, off);
  __shared__ float red[4];
  if ((threadIdx.x & 63) == 0) red[threadIdx.x >> 6] = v;
  __syncthreads();
  if (threadIdx.x == 0) {
    // analytic diagonal: n*(alpha1+alpha2) = 2/4095
    out[0] = ((red[0] + red[1]) + (red[2] + red[3])) + (float)(2.0 / 4095.0);
  }
}

extern "C" void kernel_launch(void* const* d_in, const int* in_sizes, int n_in,
                              void* d_out, int out_size, void* d_ws, size_t ws_size,
                              hipStream_t stream) {
  const float* X = (const float*)d_in[0];
  const float* Y = (const float*)d_in[1];
  float* kn        = (float*)d_ws;                        // 8192 floats (-K*norm^2)
  float* partials  = kn + 8192;                           // 2080 floats
  unsigned char* Xf = (unsigned char*)(partials + 2080);  // 512 KB fragment-native fp8
  unsigned char* Yf = Xf + (size_t)Nn * 128;              // 512 KB
  float* out = (float*)d_out;

  hipLaunchKernelGGL(prep_kernel, dim3(2048), dim3(256), 0, stream, X, Y, kn, Xf, Yf);
  hipLaunchKernelGGL(mmd_main, dim3(NBLK), dim3(256), 0, stream, Xf, Yf, kn, partials);
  hipLaunchKernelGGL(mmd_final, dim3(1), dim3(256), 0, stream, partials, out);
}